// Round 6
// baseline (396.608 us; speedup 1.0000x reference)
//
#include <hip/hip_runtime.h>

typedef unsigned short u16;
typedef unsigned int u32;
typedef __attribute__((ext_vector_type(8))) short bf16x8;
typedef __attribute__((ext_vector_type(4))) float f32x4;

__device__ __forceinline__ u16 f2bf(float f) {
    u32 u = __float_as_uint(f);
    u += 0x7fffu + ((u >> 16) & 1u);   // RNE
    return (u16)(u >> 16);
}

__device__ __forceinline__ void llds16(void* l, const void* g) {
    __builtin_amdgcn_global_load_lds(
        (const __attribute__((address_space(1))) u32*)g,
        (__attribute__((address_space(3))) u32*)l, 16, 0, 0);
}

// Padded NHWC geometry: [n][h' 0..33][w' 0..33][256ci], halo rows/cols zero.
#define PH 34
#define PIMG (PH * PH * 256)   // 295936 elems per image

// ---- prep (single dispatch): x -> padded NHWC bf16; w -> [p][co][ci] bf16;
//      BN fold; zero the halos of XT and H1 (ws is 0xAA-poisoned each call) --
__global__ void prep(const float* __restrict__ x, u16* __restrict__ xt,
                     u16* __restrict__ h1,
                     const float* __restrict__ w1, const float* __restrict__ w2,
                     u16* __restrict__ W1t, u16* __restrict__ W2t,
                     const float* __restrict__ g1, const float* __restrict__ b1,
                     const float* __restrict__ rm1, const float* __restrict__ rv1,
                     const float* __restrict__ g2, const float* __restrict__ b2,
                     const float* __restrict__ rm2, const float* __restrict__ rv2,
                     float* __restrict__ sc) {
    int t = threadIdx.x;
    int b = blockIdx.x;
    if (b < 16384) {
        // x transpose: 64 n * 32 h * 8 cb blocks; 32c x 32w tile via LDS
        __shared__ float xl[32 * 33];
        int n = b >> 8, rem = b & 255;
        int h = rem >> 3, c0 = (rem & 7) << 5;
        int cl = t >> 5, w = t & 31;
#pragma unroll
        for (int i = 0; i < 4; ++i) {
            int c = c0 + i * 8 + cl;
            xl[(i * 8 + cl) * 33 + w] = x[(n * 256 + c) * 1024 + h * 32 + w];
        }
        __syncthreads();
        int wo = t >> 3, k = t & 7;
        ushort4 o;
        o.x = f2bf(xl[(k * 4 + 0) * 33 + wo]);
        o.y = f2bf(xl[(k * 4 + 1) * 33 + wo]);
        o.z = f2bf(xl[(k * 4 + 2) * 33 + wo]);
        o.w = f2bf(xl[(k * 4 + 3) * 33 + wo]);
        *(ushort4*)&xt[(n * PIMG) + ((h + 1) * PH + (wo + 1)) * 256 + c0 + k * 4] = o;
    } else if (b < 16896) {
        int bb = b - 16384;                     // 0..511
        int idx = (bb & 255) * 256 + t;         // (co,ci) pair
        const float* src = (bb >> 8) ? w2 : w1;
        u16* dst = (bb >> 8) ? W2t : W1t;
        const float* s = src + idx * 9;
        int co = idx >> 8, ci = idx & 255;
#pragma unroll
        for (int p = 0; p < 9; ++p)
            dst[p * 65536 + co * 256 + ci] = f2bf(s[p]);
        if (bb == 0) {
            float s1 = g1[t] * rsqrtf(rv1[t] + 1e-5f);
            sc[t]       = s1;
            sc[256 + t] = b1[t] - rm1[t] * s1;
            float s2 = g2[t] * rsqrtf(rv2[t] + 1e-5f);
            sc[512 + t] = s2;
            sc[768 + t] = b2[t] - rm2[t] * s2;
        }
    } else {
        // halo zeroing: 128 blocks = 64 n x {XT, H1}; 132 halo positions each
        int bb = b - 16896;
        int n = bb >> 1;
        u16* dst = (bb & 1) ? h1 : xt;
        uint4 z; z.x = z.y = z.z = z.w = 0u;
        uint4* base = (uint4*)(dst + n * PIMG);   // 32 uint4 per position
        for (int i = t; i < 132 * 32; i += 256) {
            int pos = i >> 5, j = i & 31;
            int hh, ww;
            if (pos < 34)       { hh = 0;        ww = pos; }
            else if (pos < 68)  { hh = 33;       ww = pos - 34; }
            else if (pos < 100) { hh = pos - 67; ww = 0; }
            else                { hh = pos - 99; ww = 33; }
            base[(hh * PH + ww) * 32 + j] = z;
        }
    }
}

// ---- main: fused conv3x3 + BN (+skip) + ReLU via MFMA implicit GEMM --------
// Block: 64 c_out x (8h x 32w), 4 waves, wave = 64co x 64sp = 4x4 16x16x32.
// B (input) fragments are loaded DIRECTLY global->VGPR (16B/lane, L2-served,
// halo-padded arrays so no bounds checks) -> zero LDS bank conflicts, no
// barrier on the B path. A (weights) double-buffered in LDS via
// global_load_lds: stage kc+1 during compute of kc -> barrier drain ~0.
// XCD swizzle (bid%8) keeps the 4 co-tiles of one band on one XCD's L2.
__global__ __launch_bounds__(256, 2) void conv_mfma(
    const u16* __restrict__ Xt,    // padded NHWC bf16 input
    const u16* __restrict__ Wt,    // [9][256][256] bf16
    const float* __restrict__ sv,  // scale[256]
    const float* __restrict__ tv,  // shift[256]
    const float* __restrict__ skip,// NCHW f32 (stage2) or null
    u16* __restrict__ ybf,         // padded NHWC bf16 out (stage1)
    float* __restrict__ yf,        // NCHW f32 out (stage2)
    int stage)
{
    __shared__ alignas(16) u16 ldsA[2][9 * 4 * 64 * 8];   // 2 x 36 KB

    int t = threadIdx.x;
    int wv = t >> 6, lane = t & 63;
    int q = lane >> 4, n16 = lane & 15;

    // XCD-aware decode: bid&7 = XCD slot; co varies within a 32-bid window
    int bid = blockIdx.x;
    int co_t = (bid >> 3) & 3;
    int sp   = ((bid >> 5) << 3) | (bid & 7);   // 0..255 spatial tile
    int h_t  = sp & 3, nb = sp >> 2;
    int co0 = co_t << 6, h0 = h_t << 3;

    // A staging sources: chunk g = wv*9+i -> (p=g>>2, mt=g&3);
    // lane fetches Wt[p][co0+mt*16+n16][q*8 + kc]
    const u16* aSrc[9];
#pragma unroll
    for (int i = 0; i < 9; ++i) {
        int g = wv * 9 + i;
        int p = g >> 2, mt = g & 3;
        aSrc[i] = Wt + (p << 16) + ((co0 + (mt << 4) + n16) << 8) + (q << 3);
    }
    // B direct-load bases: (r 0..3, half 0..1) ->
    //   padded row h' = h0 + wv*2 + r, col w' = half*16 + n16, ci = q*8
    const u16* bb0[4][2];
#pragma unroll
    for (int r = 0; r < 4; ++r)
#pragma unroll
        for (int hf = 0; hf < 2; ++hf)
            bb0[r][hf] = Xt + nb * PIMG
                       + ((h0 + (wv << 1) + r) * PH + (hf << 4) + n16) * 256
                       + (q << 3);

    f32x4 acc[4][4] = {};

    // prologue: stage A[kc=0] into buffer 0
#pragma unroll
    for (int i = 0; i < 9; ++i)
        llds16(&ldsA[0][(wv * 9 + i) << 9], aSrc[i]);
    __syncthreads();

#pragma unroll 2
    for (int c = 0; c < 8; ++c) {
        const int cur = c & 1;
        if (c < 7) {
#pragma unroll
            for (int i = 0; i < 9; ++i)
                llds16(&ldsA[cur ^ 1][(wv * 9 + i) << 9], aSrc[i] + (c + 1) * 32);
        }
#pragma unroll
        for (int kw = 0; kw < 3; ++kw) {
            bf16x8 bFr[4][2];
#pragma unroll
            for (int r = 0; r < 4; ++r)
#pragma unroll
                for (int hf = 0; hf < 2; ++hf)
                    bFr[r][hf] = *(const bf16x8*)(bb0[r][hf] + c * 32 + kw * 256);
#pragma unroll
            for (int kh = 0; kh < 3; ++kh) {
                int p = kh * 3 + kw;
                bf16x8 aF[4];
#pragma unroll
                for (int mt = 0; mt < 4; ++mt)
                    aF[mt] = *(const bf16x8*)&ldsA[cur][((p << 8) + (mt << 6) + lane) << 3];
#pragma unroll
                for (int mt = 0; mt < 4; ++mt)
#pragma unroll
                    for (int nt = 0; nt < 4; ++nt)
                        acc[mt][nt] = __builtin_amdgcn_mfma_f32_16x16x32_bf16(
                            aF[mt], bFr[(nt >> 1) + kh][nt & 1], acc[mt][nt], 0, 0, 0);
            }
        }
        __syncthreads();   // emits vmcnt(0): A[c+1] staging (in flight all
                           // compute long) + consumed B loads -> drain ~0
    }

    // epilogue: C/D layout col=lane&15 (spatial w), row=q*4+reg (c_out)
    if (stage == 1) {
#pragma unroll
        for (int mt = 0; mt < 4; ++mt) {
            int cb = co0 + (mt << 4) + (q << 2);
            f32x4 ss = *(const f32x4*)&sv[cb];
            f32x4 tt = *(const f32x4*)&tv[cb];
#pragma unroll
            for (int nt = 0; nt < 4; ++nt) {
                int h = h0 + (wv << 1) + (nt >> 1), w = ((nt & 1) << 4) + n16;
                ushort4 o;
                o.x = f2bf(fmaxf(acc[mt][nt][0] * ss[0] + tt[0], 0.f));
                o.y = f2bf(fmaxf(acc[mt][nt][1] * ss[1] + tt[1], 0.f));
                o.z = f2bf(fmaxf(acc[mt][nt][2] * ss[2] + tt[2], 0.f));
                o.w = f2bf(fmaxf(acc[mt][nt][3] * ss[3] + tt[3], 0.f));
                *(ushort4*)&ybf[nb * PIMG + ((h + 1) * PH + (w + 1)) * 256 + cb] = o;
            }
        }
    } else {
#pragma unroll
        for (int mt = 0; mt < 4; ++mt) {
            int cb = co0 + (mt << 4) + (q << 2);
            f32x4 ss = *(const f32x4*)&sv[cb];
            f32x4 tt = *(const f32x4*)&tv[cb];
#pragma unroll
            for (int nt = 0; nt < 4; ++nt) {
                int h = h0 + (wv << 1) + (nt >> 1), w = ((nt & 1) << 4) + n16;
#pragma unroll
                for (int j = 0; j < 4; ++j) {
                    int idx = (((nb << 8) + cb + j) << 10) + (h << 5) + w;
                    yf[idx] = fmaxf(acc[mt][nt][j] * ss[j] + tt[j] + skip[idx], 0.f);
                }
            }
        }
    }
}

extern "C" void kernel_launch(void* const* d_in, const int* in_sizes, int n_in,
                              void* d_out, int out_size, void* d_ws, size_t ws_size,
                              hipStream_t stream) {
    const float* x   = (const float*)d_in[0];
    const float* w1  = (const float*)d_in[1];
    const float* g1  = (const float*)d_in[2];
    const float* b1  = (const float*)d_in[3];
    const float* rm1 = (const float*)d_in[4];
    const float* rv1 = (const float*)d_in[5];
    const float* w2  = (const float*)d_in[6];
    const float* g2  = (const float*)d_in[7];
    const float* b2  = (const float*)d_in[8];
    const float* rm2 = (const float*)d_in[9];
    const float* rv2 = (const float*)d_in[10];

    char* ws = (char*)d_ws;
    // padded image: 64 * 34*34*256 bf16 = 37,879,808 B each
    u16*  XT  = (u16*)(ws);                     // [0 .. 37,879,808)
    u16*  H1  = (u16*)(ws + 37879808);          // [.. 75,759,616)
    u16*  W1t = (u16*)(ws + 75759616);          // 1,179,648 B
    u16*  W2t = (u16*)(ws + 76939264);          // 1,179,648 B
    float* sc = (float*)(ws + 78118912);        // s1|t1|s2|t2, 4 KB
    if (ws_size < 78123008) return;             // workspace too small — bail

    prep<<<17024, 256, 0, stream>>>(x, XT, H1, w1, w2, W1t, W2t,
                                    g1, b1, rm1, rv1, g2, b2, rm2, rv2, sc);

    conv_mfma<<<1024, 256, 0, stream>>>(XT, W1t, sc, sc + 256, nullptr,
                                        H1, nullptr, 1);
    conv_mfma<<<1024, 256, 0, stream>>>(H1, W2t, sc + 512, sc + 768, x,
                                        nullptr, (float*)d_out, 2);
}